// Round 12
// baseline (3070.145 us; speedup 1.0000x reference)
//
#include <hip/hip_runtime.h>

typedef unsigned int u32;
typedef unsigned long long u64;

#define BN 8
#define NIMG 16                 // 2 fields (pred,tgt) * 8 batch
#define NPIMG (512*512)
#define NPIXC (NIMG*NPIMG)      // 4,194,304
#define PP (514*514)            // padded pixels per image (for label values)
#define CAP 8192u               // hash capacity per image-field (pow2)
#define SLOT0 8192
#define NSLOT 8193
#define NDN (NIMG*NSLOT)
#define TOTR 66977792u          // sum of row (=col) index over 512x512 (exact)
#define MAXL 512
#define LH 64                   // per-block LDS label-hash entries (pow2)

// ---- tiled propagation: output 96x64, ext 128x96, 16 iters/launch ---------
// 6x8 tiles/image -> 768 blocks = exactly 3 blocks/CU on 256 CUs.
#define TILE_W 96
#define TILE_H 64
#define HALO 16
#define CF4 32                  // 128/4 float4 cols = one 32-lane row group
#define NSTRIP 8                // strips of 12 rows (ext height 96)
#define SROWS 12
#define TPC 6
#define TPR 8
#define TPT (TPR*TPC)           // 48 tiles per image
#define PROPBLOCKS (NIMG*TPT)   // 768

__device__ __forceinline__ u32 hashL(u32 L) { return (L * 2654435761u) >> 19; }
__device__ __forceinline__ u32 hashS(u32 L) { return (L * 2654435761u) >> 26; }

// monotone map double -> u64 so unsigned min == double min
__device__ __forceinline__ u64 encAng(double a) {
  u64 u = (u64)__double_as_longlong(a);
  return (u >> 63) ? ~u : (u | 0x8000000000000000ull);
}

__device__ __forceinline__ float fmax3(float a, float b, float c) {
  return fmaxf(a, fmaxf(b, c));
}

// horizontal 3-max within a 32-lane row group; tile-edge cells forced 0
// (halo-invalid; contamination ring stays outside the inner output tile)
__device__ __forceinline__ float4 horizf4(float4 M, int tx) {
  float Lw = __shfl_up(M.w, 1);
  float Rx = __shfl_down(M.x, 1);
  if (tx == 0) Lw = 0.f;
  if (tx == CF4 - 1) Rx = 0.f;
  float4 hh;
  hh.x = fmax3(Lw, M.x, M.y);
  hh.y = fmax3(M.x, M.y, M.z);
  hh.z = fmax3(M.y, M.z, M.w);
  hh.w = fmax3(M.z, M.w, Rx);
  return hh;
}

// init label value for a float4 cell at (gr, gc) of image-field img
__device__ __forceinline__ float4 initVal(const float* __restrict__ pred,
                                          const float* __restrict__ tgt,
                                          int img, int gr, int gc) {
  const int f = img >> 3, b = img & 7;
  const float* fb = (f == 0 ? pred : tgt) + b * NPIMG;
  float4 x = *(const float4*)(fb + gr * 512 + gc);
  float lb = (float)(b * PP + (gr + 1) * 514 + (gc + 1));
  bool mx, my, mz, mw;
  if (f == 0) { mx = x.x > 0.f; my = x.y > 0.f; mz = x.z > 0.f; mw = x.w > 0.f; }
  else        { mx = x.x == 1.f; my = x.y == 1.f; mz = x.z == 1.f; mw = x.w == 1.f; }
  float4 v;
  v.x = mx ? lb : 0.f;
  v.y = my ? lb + 1.f : 0.f;
  v.z = mz ? lb + 2.f : 0.f;
  v.w = mw ? lb + 3.f : 0.f;
  return v;
}

// ---------------- k iterations of masked 3x3 max, register strips -----------
// Thread (sy,tx) owns a 12-row x 1-float4 strip of the 128x96 extended tile
// whose inner 96x64 is the output tile. first=1: build labels from pred/tgt.
__global__ __launch_bounds__(256) void k_prop(const float* __restrict__ src,
                                              float* __restrict__ dst,
                                              const float* __restrict__ pred,
                                              const float* __restrict__ tgt,
                                              int niter, int first) {
  __shared__ float4 hTopS[2][NSTRIP][CF4];   // h row 0 of each strip
  __shared__ float4 hBotS[2][NSTRIP][CF4];   // h row SROWS-1 of each strip
  __shared__ int s_flag;
  const int tid = threadIdx.x;
  const int bx = blockIdx.x;
  // XCD-aware decode: bx&7 -> image pair (round-robin block->XCD heuristic)
  const int j = bx >> 3;
  const int img = ((bx & 7) << 1) + (j >= TPT ? 1 : 0);
  const int tt = (j >= TPT) ? (j - TPT) : j;
  const int tyT = tt / TPC, txT = tt % TPC;
  const int tx = tid & 31, sy = tid >> 5;
  const int gr0 = tyT * TILE_H - HALO + sy * SROWS;
  const int gc = txT * TILE_W - HALO + tx * 4;     // float4 fully in or out
  const bool gcok = (gc >= 0 && gc < 512);

  float4 cur[SROWS];
  if (first) {
#pragma unroll
    for (int r = 0; r < SROWS; ++r) {
      float4 v = make_float4(0.f, 0.f, 0.f, 0.f);
      int gr = gr0 + r;
      if (gcok && gr >= 0 && gr < 512)
        v = initVal(pred, tgt, img, gr, gc);
      cur[r] = v;
    }
  } else {
    const float* ibase = src + img * NPIMG;
#pragma unroll
    for (int r = 0; r < SROWS; ++r) {
      float4 v = make_float4(0.f, 0.f, 0.f, 0.f);
      int gr = gr0 + r;
      if (gcok && gr >= 0 && gr < 512)
        v = *(const float4*)(ibase + gr * 512 + gc);
      cur[r] = v;
    }
  }

  bool changed = false;
  for (int itr = 0; itr < niter; ++itr) {
    const int p = itr & 1;
    const bool chk = ((itr & 3) == 3);           // fixpoint test every 4 iters
    float4 h[SROWS];
#pragma unroll
    for (int r = 0; r < SROWS; ++r) h[r] = horizf4(cur[r], tx);
    hTopS[p][sy][tx] = h[0];
    hBotS[p][sy][tx] = h[SROWS - 1];
    if (chk && tid == 0) s_flag = 0;             // finalized before B1
    __syncthreads();                             // B1
    float4 zero = make_float4(0.f, 0.f, 0.f, 0.f);
    float4 hm = (sy > 0) ? hBotS[p][sy - 1][tx] : zero;
    float4 below = (sy < NSTRIP - 1) ? hTopS[p][sy + 1][tx] : zero;
#pragma unroll
    for (int r = 0; r < SROWS; ++r) {
      float4 hc = h[r];
      float4 hp = (r == SROWS - 1) ? below : h[r + 1];
      float4 o = cur[r], v;
      v.x = (o.x > 0.f) ? fmax3(hm.x, hc.x, hp.x) : 0.f;
      v.y = (o.y > 0.f) ? fmax3(hm.y, hc.y, hp.y) : 0.f;
      v.z = (o.z > 0.f) ? fmax3(hm.z, hc.z, hp.z) : 0.f;
      v.w = (o.w > 0.f) ? fmax3(hm.w, hc.w, hp.w) : 0.f;
      if (chk)
        changed = changed || (v.x != o.x) || (v.y != o.y) || (v.z != o.z) || (v.w != o.w);
      cur[r] = v;
      hm = hc;
    }
    if (chk) {
      if (changed) s_flag = 1;                   // benign race: all write 1
      __syncthreads();                           // B2 (check iters only)
      if (s_flag == 0) break;                    // no change at iter itr -> identity
      changed = false;
    }
  }

  // writeback inner 96x64 from registers (coalesced 16B stores)
  if (tx >= 4 && tx <= 27 && gc < 512) {
    float* obase = dst + img * NPIMG;
#pragma unroll
    for (int r = 0; r < SROWS; ++r) {
      int er = sy * SROWS + r;
      if (er >= HALO && er < HALO + TILE_H)
        *(float4*)(obase + (gr0 + r) * 512 + gc) = cur[r];
    }
  }
}

// ---- final fused launch: 4 iters + boundary + Cm write + label stats -------
// Ring after 4 iters is 4 < HALO-1, so ext registers are exact at inner+-1:
// the 3x3-min boundary of every inner cell is computable in-register.
__global__ __launch_bounds__(256) void k_prop_cimg(const float* __restrict__ src,
                                                   float* __restrict__ Cm,
                                                   u32* __restrict__ key, u32* __restrict__ cnt,
                                                   u32* __restrict__ sr, u32* __restrict__ sc,
                                                   int niter) {
  __shared__ float4 hTopS[2][NSTRIP][CF4];
  __shared__ float4 hBotS[2][NSTRIP][CF4];
  __shared__ float4 vTop[NSTRIP][CF4];       // cur row 0 of each strip
  __shared__ float4 vBot[NSTRIP][CF4];       // cur row SROWS-1 of each strip
  __shared__ u32 hl[LH], hn[LH], hr[LH], hc2[LH];
  __shared__ u32 s_n, s_r, s_c;
  const int tid = threadIdx.x;
  const int bx = blockIdx.x;
  const int j = bx >> 3;
  const int img = ((bx & 7) << 1) + (j >= TPT ? 1 : 0);
  const int tt = (j >= TPT) ? (j - TPT) : j;
  const int tyT = tt / TPC, txT = tt % TPC;
  const int tx = tid & 31, sy = tid >> 5;
  const int gr0 = tyT * TILE_H - HALO + sy * SROWS;
  const int gc = txT * TILE_W - HALO + tx * 4;
  const bool gcok = (gc >= 0 && gc < 512);
  const bool writer = (tx >= 4 && tx <= 27 && gc < 512);

  for (int e = tid; e < LH; e += 256) { hl[e] = 0; hn[e] = 0; hr[e] = 0; hc2[e] = 0; }
  if (tid == 0) { s_n = 0; s_r = 0; s_c = 0; }

  float4 cur[SROWS];
  {
    const float* ibase = src + img * NPIMG;
#pragma unroll
    for (int r = 0; r < SROWS; ++r) {
      float4 v = make_float4(0.f, 0.f, 0.f, 0.f);
      int gr = gr0 + r;
      if (gcok && gr >= 0 && gr < 512)
        v = *(const float4*)(ibase + gr * 512 + gc);
      cur[r] = v;
    }
  }

  for (int itr = 0; itr < niter; ++itr) {      // 4 iters, no fixpoint checks
    const int p = itr & 1;
    float4 h[SROWS];
#pragma unroll
    for (int r = 0; r < SROWS; ++r) h[r] = horizf4(cur[r], tx);
    hTopS[p][sy][tx] = h[0];
    hBotS[p][sy][tx] = h[SROWS - 1];
    __syncthreads();
    float4 zero = make_float4(0.f, 0.f, 0.f, 0.f);
    float4 hm = (sy > 0) ? hBotS[p][sy - 1][tx] : zero;
    float4 below = (sy < NSTRIP - 1) ? hTopS[p][sy + 1][tx] : zero;
#pragma unroll
    for (int r = 0; r < SROWS; ++r) {
      float4 hc = h[r];
      float4 hp = (r == SROWS - 1) ? below : h[r + 1];
      float4 o = cur[r], v;
      v.x = (o.x > 0.f) ? fmax3(hm.x, hc.x, hp.x) : 0.f;
      v.y = (o.y > 0.f) ? fmax3(hm.y, hc.y, hp.y) : 0.f;
      v.z = (o.z > 0.f) ? fmax3(hm.z, hc.z, hp.z) : 0.f;
      v.w = (o.w > 0.f) ? fmax3(hm.w, hc.w, hp.w) : 0.f;
      cur[r] = v;
      hm = hc;
    }
    __syncthreads();                           // protect hTopS reuse next iter
  }

  // exchange value rows across strip boundaries for the vertical neighbors
  vTop[sy][tx] = cur[0];
  vBot[sy][tx] = cur[SROWS - 1];
  __syncthreads();
  float4 zero = make_float4(0.f, 0.f, 0.f, 0.f);
  float4 above = (sy > 0) ? vBot[sy - 1][tx] : zero;
  float4 belowV = (sy < NSTRIP - 1) ? vTop[sy + 1][tx] : zero;

  // boundary + Cm write + per-label stats over the inner tile
  float* cb = Cm + img * NPIMG;
#pragma unroll
  for (int r = 0; r < SROWS; ++r) {
    int er = sy * SROWS + r;
    if (er < HALO || er >= HALO + TILE_H) continue;
    float4 U = (r == 0) ? above : cur[r - 1];
    float4 D = (r == SROWS - 1) ? belowV : cur[r + 1];
    float4 M = cur[r];
    float LwU = __shfl_up(U.w, 1), RxU = __shfl_down(U.x, 1);
    float LwM = __shfl_up(M.w, 1), RxM = __shfl_down(M.x, 1);
    float LwD = __shfl_up(D.w, 1), RxD = __shfl_down(D.x, 1);
    if (!writer) continue;                     // inner lanes only (tx 4..27)
    float4 mn, out;
    mn.x = fminf(fminf(fminf(LwU, U.x), fminf(U.y, LwM)),
                 fminf(fminf(M.y, LwD), fminf(D.x, D.y)));
    mn.y = fminf(fminf(fminf(U.x, U.y), fminf(U.z, M.x)),
                 fminf(fminf(M.z, D.x), fminf(D.y, D.z)));
    mn.z = fminf(fminf(fminf(U.y, U.z), fminf(U.w, M.y)),
                 fminf(fminf(M.w, D.y), fminf(D.z, D.w)));
    mn.w = fminf(fminf(fminf(U.z, U.w), fminf(RxU, M.z)),
                 fminf(fminf(RxM, D.z), fminf(D.w, RxD)));
    out.x = (M.x > 0.f && mn.x == 0.f) ? M.x : 0.f;
    out.y = (M.y > 0.f && mn.y == 0.f) ? M.y : 0.f;
    out.z = (M.z > 0.f && mn.z == 0.f) ? M.z : 0.f;
    out.w = (M.w > 0.f && mn.w == 0.f) ? M.w : 0.f;
    *(float4*)(cb + (gr0 + r) * 512 + gc) = out;
    // stats for nonzero contour pixels
    int gr = gr0 + r;
#pragma unroll
    for (int comp = 0; comp < 4; ++comp) {
      float ov = (comp == 0) ? out.x : (comp == 1) ? out.y : (comp == 2) ? out.z : out.w;
      if (ov == 0.f) continue;
      u32 L = (u32)ov;
      u32 rr = (u32)gr, cc = (u32)(gc + comp);
      u32 h = hashS(L);
      for (u32 pr = 0; pr < LH; ++pr) {
        u32 e = (h + pr) & (LH - 1);
        u32 k = atomicCAS(&hl[e], 0u, L);
        if (k == 0u || k == L) {
          atomicAdd(&hn[e], 1u); atomicAdd(&hr[e], rr); atomicAdd(&hc2[e], cc);
          break;
        }
      }
      atomicAdd(&s_n, 1u); atomicAdd(&s_r, rr); atomicAdd(&s_c, cc);
    }
  }
  __syncthreads();
  // flush LDS label table to the global hash (one probe per distinct label)
  for (int e = tid; e < LH; e += 256) {
    u32 L = hl[e];
    if (L == 0u) continue;
    u32 hg = hashL(L), slot = 0xFFFFFFFFu;
    for (u32 pr = 0; pr < CAP; ++pr) {
      u32 k = key[img * CAP + hg];
      if (k == L) { slot = hg; break; }
      if (k == 0u) {
        u32 old = atomicCAS(&key[img * CAP + hg], 0u, L);
        if (old == 0u || old == L) { slot = hg; break; }
      }
      hg = (hg + 1) & (CAP - 1);
    }
    if (slot != 0xFFFFFFFFu) {
      u32 s = (u32)img * NSLOT + slot;
      atomicAdd(&cnt[s], hn[e]); atomicAdd(&sr[s], hr[e]); atomicAdd(&sc[s], hc2[e]);
    }
  }
  if (tid == 0 && s_n) {
    u32 s = (u32)img * NSLOT + SLOT0;
    atomicAdd(&cnt[s], s_n); atomicAdd(&sr[s], s_r); atomicAdd(&sc[s], s_c);
  }
}

// ------- compact occupied hash slots (+label 0) into dense per-image lists --
__global__ __launch_bounds__(256) void k_compact(const u32* __restrict__ key,
                                                 const u32* __restrict__ cnt,
                                                 const u32* __restrict__ sr, const u32* __restrict__ sc,
                                                 u32* __restrict__ nlab, u32* __restrict__ labD,
                                                 u32* __restrict__ cntD, u32* __restrict__ srD,
                                                 u32* __restrict__ scD, u32* __restrict__ slotD) {
  int i = blockIdx.x * 256 + threadIdx.x;
  if (i >= NDN) return;
  int img = i / NSLOT, s = i - img * NSLOT;
  u32 L, n, a, b2;
  if (s < (int)CAP) {
    L = key[img * CAP + s];
    if (L == 0u) return;
    n = cnt[img * NSLOT + s];
    a = sr[img * NSLOT + s]; b2 = sc[img * NSLOT + s];
  } else {
    u32 nn = cnt[img * NSLOT + SLOT0];
    n = NPIMG - nn;                     // label-0 (background) pixel count
    if (n == 0u) return;
    L = 0u;
    a = TOTR - sr[img * NSLOT + SLOT0]; b2 = TOTR - sc[img * NSLOT + SLOT0];
  }
  u32 j = atomicAdd(&nlab[img], 1u);
  if (j < MAXL) {
    labD[img * MAXL + j] = L; cntD[img * MAXL + j] = n;
    srD[img * MAXL + j] = a;  scD[img * MAXL + j] = b2;
    slotD[img * MAXL + j] = (u32)s;
  }
}

// ---------------- pass 2: per-label min encoded angle (LDS slot agg) --------
__global__ __launch_bounds__(256) void k_angle(const float* __restrict__ Cm,
                                               const u32* __restrict__ key, const u32* __restrict__ cnt,
                                               const u32* __restrict__ sr, const u32* __restrict__ sc,
                                               u64* __restrict__ amin) {
  __shared__ u32 asl[LH];
  __shared__ u64 amn[LH];
  __shared__ u64 wmin[4];
  const int tid = threadIdx.x;
  for (int e = tid; e < LH; e += 256) { asl[e] = 0; amn[e] = ~0ull; }
  __syncthreads();
  int i = blockIdx.x * 256 + tid;
  int img = i >> 18, q = i & (NPIMG - 1);
  int r = q >> 9, c = q & 511;
  float v = Cm[i];
  u64 e0 = ~0ull;
  if (v == 0.f) {
    u32 base = (u32)img * NSLOT + SLOT0;
    u32 n0 = NPIMG - cnt[base];                   // >=1 since this pixel is zero
    double cr = (double)(TOTR - sr[base]) / (double)n0;
    double cc = (double)(TOTR - sc[base]) / (double)n0;
    e0 = encAng(atan2((double)c - cc, (double)r - cr));
  } else {
    u32 L = (u32)v;
    u32 h = hashL(L);
    for (u32 pr = 0; pr < CAP && key[img * CAP + h] != L; ++pr) h = (h + 1) & (CAP - 1);
    u32 s = (u32)img * NSLOT + h;
    u32 n = cnt[s];
    double cr = (double)sr[s] / (double)n;
    double cc = (double)sc[s] / (double)n;
    u64 enc = encAng(atan2((double)c - cc, (double)r - cr));
    u32 kk = h + 1, hh = hashS(kk);
    bool ins = false;
    for (u32 pr = 0; pr < LH; ++pr) {
      u32 e = (hh + pr) & (LH - 1);
      u32 k = atomicCAS(&asl[e], 0u, kk);
      if (k == 0u || k == kk) { atomicMin(&amn[e], enc); ins = true; break; }
    }
    if (!ins) atomicMin(&amin[s], enc);
  }
  // block-reduce the hot label-0 slot to 1 atomic/block
  for (int o = 32; o > 0; o >>= 1) {
    u64 other = __shfl_xor(e0, o, 64);
    e0 = other < e0 ? other : e0;
  }
  int lane = tid & 63, wid = tid >> 6;
  if (lane == 0) wmin[wid] = e0;
  __syncthreads();
  int im = (blockIdx.x * 256) >> 18;
  if (tid == 0) {
    u64 m = wmin[0];
    for (int k = 1; k < 4; ++k) m = wmin[k] < m ? wmin[k] : m;
    if (m != ~0ull) atomicMin(&amin[(u32)im * NSLOT + SLOT0], m);
  }
  for (int e = tid; e < LH; e += 256)
    if (asl[e]) atomicMin(&amin[(u32)im * NSLOT + (asl[e] - 1)], amn[e]);
}

// ---------------- pass 3: min row-major index among min-angle points --------
__global__ __launch_bounds__(256) void k_idx(const float* __restrict__ Cm,
                                             const u32* __restrict__ key, const u32* __restrict__ cnt,
                                             const u32* __restrict__ sr, const u32* __restrict__ sc,
                                             const u64* __restrict__ amin, u32* __restrict__ imin) {
  __shared__ u32 isl[LH];
  __shared__ u32 imn[LH];
  const int tid = threadIdx.x;
  for (int e = tid; e < LH; e += 256) { isl[e] = 0; imn[e] = 0xFFFFFFFFu; }
  __syncthreads();
  int i = blockIdx.x * 256 + tid;
  int img = i >> 18, q = i & (NPIMG - 1);
  int r = q >> 9, c = q & 511;
  float v = Cm[i];
  u32 sl; double cr, cc;
  if (v == 0.f) {
    sl = SLOT0;
    u32 s = (u32)img * NSLOT + SLOT0;
    u32 n0 = NPIMG - cnt[s];
    cr = (double)(TOTR - sr[s]) / (double)n0;
    cc = (double)(TOTR - sc[s]) / (double)n0;
  } else {
    u32 L = (u32)v;
    u32 h = hashL(L);
    for (u32 pr = 0; pr < CAP && key[img * CAP + h] != L; ++pr) h = (h + 1) & (CAP - 1);
    sl = h;
    u32 s = (u32)img * NSLOT + h;
    u32 n = cnt[s];
    cr = (double)sr[s] / (double)n;
    cc = (double)sc[s] / (double)n;
  }
  u64 e = encAng(atan2((double)c - cc, (double)r - cr));
  if (e == amin[(u32)img * NSLOT + sl]) {
    u32 kk = sl + 1, hh = hashS(kk);
    bool ins = false;
    for (u32 pr = 0; pr < LH; ++pr) {
      u32 e2 = (hh + pr) & (LH - 1);
      u32 k = atomicCAS(&isl[e2], 0u, kk);
      if (k == 0u || k == kk) { atomicMin(&imn[e2], (u32)q); ins = true; break; }
    }
    if (!ins) atomicMin(&imin[(u32)img * NSLOT + sl], (u32)q);
  }
  __syncthreads();
  int im = (blockIdx.x * 256) >> 18;
  for (int e2 = tid; e2 < LH; e2 += 256)
    if (isl[e2]) atomicMin(&imin[(u32)im * NSLOT + (isl[e2] - 1)], imn[e2]);
}

// ------- gather dense lists, parallel rank-sort, parallel match -------------
__global__ __launch_bounds__(256) void k_match(const u32* __restrict__ nlab,
                                               const u32* __restrict__ labD, const u32* __restrict__ cntD,
                                               const u32* __restrict__ srD, const u32* __restrict__ scD,
                                               const u32* __restrict__ slotD, const u32* __restrict__ imin,
                                               const float* __restrict__ wp, float* __restrict__ out) {
  __shared__ u32 lbl[2][MAXL];
  __shared__ double cx[2][MAXL], cy[2][MAXL], Rr[2][MAXL];
  __shared__ int nlist[2];
  __shared__ double wsum[4];
  const int tid = threadIdx.x;
  double S = 0.0;                        // per-thread partial
  for (int b = 0; b < BN; ++b) {
    __syncthreads();
    if (tid == 0) { nlist[0] = nlist[1] = 0; }
    __syncthreads();
    int tot[2];
    for (int f = 0; f < 2; ++f) {
      int t = f * BN + b;
      int ntot = (int)nlab[t];
      tot[f] = ntot;                     // unique-label count (pre-MIN_PTS)
      int nl = ntot > MAXL ? MAXL : ntot;
      for (int s2 = tid; s2 < nl; s2 += 256) {
        u32 n = cntD[t * MAXL + s2];
        if (n < 10u) continue;
        int j = atomicAdd(&nlist[f], 1); // j < MAXL guaranteed
        lbl[f][j] = labD[t * MAXL + s2];
        cx[f][j] = (double)srD[t * MAXL + s2] / (double)n;
        cy[f][j] = (double)scD[t * MAXL + s2] / (double)n;
        u32 pi = imin[t * NSLOT + slotD[t * MAXL + s2]];
        double r0 = (double)(pi >> 9), c0 = (double)(pi & 511u);
        Rr[f][j] = sqrt(r0 * r0 + c0 * c0);
      }
    }
    __syncthreads();
    int np = nlist[0], nt = nlist[1];
    bool valid = (tot[0] >= 2) && (np >= 1) && (tot[1] >= 2) && (nt >= 1);
    if (valid) {
      // parallel rank sort (labels unique -> rank is a permutation)
      u32 ml[2][2]; double mx[2][2], my[2][2], mr[2][2]; int rk[2][2]; int nh[2];
      for (int f = 0; f < 2; ++f) {
        int n = f ? nt : np;
        nh[f] = 0;
        for (int i = tid; i < n; i += 256) {
          int k = nh[f]++;
          u32 L = lbl[f][i];
          ml[f][k] = L; mx[f][k] = cx[f][i]; my[f][k] = cy[f][i]; mr[f][k] = Rr[f][i];
          int rr = 0;
          for (int j = 0; j < n; ++j) rr += (lbl[f][j] < L) ? 1 : 0;
          rk[f][k] = rr;
        }
      }
      __syncthreads();
      for (int f = 0; f < 2; ++f)
        for (int k = 0; k < nh[f]; ++k) {
          int rr = rk[f][k];
          lbl[f][rr] = ml[f][k]; cx[f][rr] = mx[f][k];
          cy[f][rr] = my[f][k];  Rr[f][rr] = mr[f][k];
        }
      __syncthreads();
      // parallel nearest-center match over rows of the smaller list
      if (nt <= np) {
        for (int j = tid; j < nt; j += 256) {
          int m = 0; double bd = 1e300;
          double tx0 = cx[1][j], ty0 = cy[1][j];
          for (int i2 = 0; i2 < np; ++i2) {
            double dx = tx0 - cx[0][i2], dy = ty0 - cy[0][i2];
            double d = dx * dx + dy * dy;
            if (d < bd) { bd = d; m = i2; }
          }
          S += fabs(Rr[0][m] - Rr[1][j]);
        }
      } else {
        for (int i2 = tid; i2 < np; i2 += 256) {
          int m = 0; double bd = 1e300;
          double px0 = cx[0][i2], py0 = cy[0][i2];
          for (int j = 0; j < nt; ++j) {
            double dx = px0 - cx[1][j], dy = py0 - cy[1][j];
            double d = dx * dx + dy * dy;
            if (d < bd) { bd = d; m = j; }
          }
          S += fabs(Rr[1][m] - Rr[0][i2]);
        }
      }
    }
  }
  // block-reduce per-thread partials
  for (int o = 32; o > 0; o >>= 1) S += __shfl_xor(S, o, 64);
  int lane = tid & 63, wid = tid >> 6;
  if (lane == 0) wsum[wid] = S;
  __syncthreads();
  if (tid == 0) {
    double total = wsum[0] + wsum[1] + wsum[2] + wsum[3];
    total *= (1.5 / 3.14159265358979323846);   // sum_k 1/(k*pi), k=1,2
    float w = wp[0];
    out[0] = (float)total * (0.5f * w * w);
  }
}

extern "C" void kernel_launch(void* const* d_in, const int* in_sizes, int n_in,
                              void* d_out, int out_size, void* d_ws, size_t ws_size,
                              hipStream_t stream) {
  const float* pred = (const float*)d_in[0];
  const float* tgt  = (const float*)d_in[1];
  const float* wp   = (const float*)d_in[2];
  float* out = (float*)d_out;

  char* ws = (char*)d_ws;
  size_t off = 0;
  float* A  = (float*)(ws + off); off += (size_t)NPIXC * 4;
  float* Bb = (float*)(ws + off); off += (size_t)NPIXC * 4;
  u32* key  = (u32*)(ws + off);   off += (size_t)NIMG * CAP * 4;
  u32* cnt  = (u32*)(ws + off);   off += (size_t)NIMG * NSLOT * 4;
  u32* sr   = (u32*)(ws + off);   off += (size_t)NIMG * NSLOT * 4;
  u32* sc   = (u32*)(ws + off);   off += (size_t)NIMG * NSLOT * 4;
  u64* amin = (u64*)(ws + off);   off += (size_t)NIMG * NSLOT * 8;
  u32* imin = (u32*)(ws + off);   off += (size_t)NIMG * NSLOT * 4;
  u32* nlab = (u32*)(ws + off);   off += (size_t)NIMG * 4;
  u32* labD = (u32*)(ws + off);   off += (size_t)NIMG * MAXL * 4;
  u32* cntD = (u32*)(ws + off);   off += (size_t)NIMG * MAXL * 4;
  u32* srD  = (u32*)(ws + off);   off += (size_t)NIMG * MAXL * 4;
  u32* scD  = (u32*)(ws + off);   off += (size_t)NIMG * MAXL * 4;
  u32* slotD= (u32*)(ws + off);   off += (size_t)NIMG * MAXL * 4;

  size_t zlen = (size_t)NIMG * CAP * 4 + 3ull * NIMG * NSLOT * 4;
  hipMemsetAsync(key, 0, zlen, stream);
  hipMemsetAsync(amin, 0xFF, (size_t)NIMG * NSLOT * 12, stream);
  hipMemsetAsync(nlab, 0, (size_t)NIMG * 4, stream);

  const int gC = NPIXC / 256;            // exact
  const int gS = (NDN + 255) / 256;      // slot-compaction grid

  // 31 launches x 16 iters = 496, then fused final launch does 4 more (=500)
  k_prop<<<PROPBLOCKS, 256, 0, stream>>>(A, A, pred, tgt, 16, 1);
  float* src = A; float* dst = Bb;
  for (int s = 1; s <= 30; ++s) {
    k_prop<<<PROPBLOCKS, 256, 0, stream>>>(src, dst, pred, tgt, 16, 0);
    float* t2 = src; src = dst; dst = t2;
  }
  // after 31 launches, state is in src; final fused launch writes Cm into dst
  float* Cm = dst;
  k_prop_cimg<<<PROPBLOCKS, 256, 0, stream>>>(src, Cm, key, cnt, sr, sc, 4);
  k_compact<<<gS, 256, 0, stream>>>(key, cnt, sr, sc, nlab, labD, cntD, srD, scD, slotD);
  k_angle<<<gC, 256, 0, stream>>>(Cm, key, cnt, sr, sc, amin);
  k_idx<<<gC, 256, 0, stream>>>(Cm, key, cnt, sr, sc, amin, imin);
  k_match<<<1, 256, 0, stream>>>(nlab, labD, cntD, srD, scD, slotD, imin, wp, out);
}

// Round 13
// 1459.483 us; speedup vs baseline: 2.1036x; 2.1036x over previous
//
#include <hip/hip_runtime.h>

typedef unsigned int u32;
typedef unsigned long long u64;

#define BN 8
#define NIMG 16                 // 2 fields (pred,tgt) * 8 batch
#define NPIMG (512*512)
#define NPIXC (NIMG*NPIMG)      // 4,194,304
#define PP (514*514)            // padded pixels per image (for label values)
#define CAP 8192u               // hash capacity per image-field (pow2)
#define SLOT0 8192
#define NSLOT 8193
#define NDN (NIMG*NSLOT)
#define TOTR 66977792u          // sum of row (=col) index over 512x512 (exact)
#define MAXL 512
#define PROP_ITERS 500
#define LH 64                   // per-block LDS label-hash entries (pow2)

// ---- tiled propagation: output 96x64, ext 128x96, 16 iters/launch ---------
// 6x8 tiles/image -> 768 blocks = exactly 3 blocks/CU on 256 CUs.
#define TILE_W 96
#define TILE_H 64
#define HALO 16
#define CF4 32                  // 128/4 float4 cols = one 32-lane row group
#define NSTRIP 8                // strips of 12 rows (ext height 96)
#define SROWS 12
#define TPC 6
#define TPR 8
#define TPT (TPR*TPC)           // 48 tiles per image
#define PROPBLOCKS (NIMG*TPT)   // 768

__device__ __forceinline__ u32 hashL(u32 L) { return (L * 2654435761u) >> 19; }
__device__ __forceinline__ u32 hashS(u32 L) { return (L * 2654435761u) >> 26; }

// monotone map double -> u64 so unsigned min == double min
__device__ __forceinline__ u64 encAng(double a) {
  u64 u = (u64)__double_as_longlong(a);
  return (u >> 63) ? ~u : (u | 0x8000000000000000ull);
}

__device__ __forceinline__ float fmax3(float a, float b, float c) {
  return fmaxf(a, fmaxf(b, c));
}

// horizontal 3-max within a 32-lane row group; tile-edge cells forced 0
// (halo-invalid; contamination ring stays outside the inner output tile)
__device__ __forceinline__ float4 horizf4(float4 M, int tx) {
  float Lw = __shfl_up(M.w, 1);
  float Rx = __shfl_down(M.x, 1);
  if (tx == 0) Lw = 0.f;
  if (tx == CF4 - 1) Rx = 0.f;
  float4 hh;
  hh.x = fmax3(Lw, M.x, M.y);
  hh.y = fmax3(M.x, M.y, M.z);
  hh.z = fmax3(M.y, M.z, M.w);
  hh.w = fmax3(M.z, M.w, Rx);
  return hh;
}

// init label value for a float4 cell at (gr, gc) of image-field img
__device__ __forceinline__ float4 initVal(const float* __restrict__ pred,
                                          const float* __restrict__ tgt,
                                          int img, int gr, int gc) {
  const int f = img >> 3, b = img & 7;
  const float* fb = (f == 0 ? pred : tgt) + b * NPIMG;
  float4 x = *(const float4*)(fb + gr * 512 + gc);
  float lb = (float)(b * PP + (gr + 1) * 514 + (gc + 1));
  bool mx, my, mz, mw;
  if (f == 0) { mx = x.x > 0.f; my = x.y > 0.f; mz = x.z > 0.f; mw = x.w > 0.f; }
  else        { mx = x.x == 1.f; my = x.y == 1.f; mz = x.z == 1.f; mw = x.w == 1.f; }
  float4 v;
  v.x = mx ? lb : 0.f;
  v.y = my ? lb + 1.f : 0.f;
  v.z = mz ? lb + 2.f : 0.f;
  v.w = mw ? lb + 3.f : 0.f;
  return v;
}

// ---------------- k iterations of masked 3x3 max, register strips -----------
// Thread (sy,tx) owns a 12-row x 1-float4 strip of the 128x96 extended tile
// whose inner 96x64 is the output tile. first=1: build labels from pred/tgt.
__global__ __launch_bounds__(256) void k_prop(const float* __restrict__ src,
                                              float* __restrict__ dst,
                                              const float* __restrict__ pred,
                                              const float* __restrict__ tgt,
                                              int niter, int first) {
  __shared__ float4 hTopS[2][NSTRIP][CF4];   // h row 0 of each strip
  __shared__ float4 hBotS[2][NSTRIP][CF4];   // h row SROWS-1 of each strip
  __shared__ int s_flag;
  const int tid = threadIdx.x;
  const int bx = blockIdx.x;
  // XCD-aware decode: bx&7 -> image pair (round-robin block->XCD heuristic)
  const int j = bx >> 3;
  const int img = ((bx & 7) << 1) + (j >= TPT ? 1 : 0);
  const int tt = (j >= TPT) ? (j - TPT) : j;
  const int tyT = tt / TPC, txT = tt % TPC;
  const int tx = tid & 31, sy = tid >> 5;
  const int gr0 = tyT * TILE_H - HALO + sy * SROWS;
  const int gc = txT * TILE_W - HALO + tx * 4;     // float4 fully in or out
  const bool gcok = (gc >= 0 && gc < 512);

  float4 cur[SROWS];
  if (first) {
#pragma unroll
    for (int r = 0; r < SROWS; ++r) {
      float4 v = make_float4(0.f, 0.f, 0.f, 0.f);
      int gr = gr0 + r;
      if (gcok && gr >= 0 && gr < 512)
        v = initVal(pred, tgt, img, gr, gc);
      cur[r] = v;
    }
  } else {
    const float* ibase = src + img * NPIMG;
#pragma unroll
    for (int r = 0; r < SROWS; ++r) {
      float4 v = make_float4(0.f, 0.f, 0.f, 0.f);
      int gr = gr0 + r;
      if (gcok && gr >= 0 && gr < 512)
        v = *(const float4*)(ibase + gr * 512 + gc);
      cur[r] = v;
    }
  }

  bool changed = false;
  for (int itr = 0; itr < niter; ++itr) {
    const int p = itr & 1;
    const bool chk = ((itr & 3) == 3);           // fixpoint test every 4 iters
    float4 h[SROWS];
#pragma unroll
    for (int r = 0; r < SROWS; ++r) h[r] = horizf4(cur[r], tx);
    hTopS[p][sy][tx] = h[0];
    hBotS[p][sy][tx] = h[SROWS - 1];
    if (chk && tid == 0) s_flag = 0;             // finalized before B1
    __syncthreads();                             // B1
    float4 zero = make_float4(0.f, 0.f, 0.f, 0.f);
    float4 hm = (sy > 0) ? hBotS[p][sy - 1][tx] : zero;
    float4 below = (sy < NSTRIP - 1) ? hTopS[p][sy + 1][tx] : zero;
#pragma unroll
    for (int r = 0; r < SROWS; ++r) {
      float4 hc = h[r];
      float4 hp = (r == SROWS - 1) ? below : h[r + 1];
      float4 o = cur[r], v;
      v.x = (o.x > 0.f) ? fmax3(hm.x, hc.x, hp.x) : 0.f;
      v.y = (o.y > 0.f) ? fmax3(hm.y, hc.y, hp.y) : 0.f;
      v.z = (o.z > 0.f) ? fmax3(hm.z, hc.z, hp.z) : 0.f;
      v.w = (o.w > 0.f) ? fmax3(hm.w, hc.w, hp.w) : 0.f;
      if (chk)
        changed = changed || (v.x != o.x) || (v.y != o.y) || (v.z != o.z) || (v.w != o.w);
      cur[r] = v;
      hm = hc;
    }
    if (chk) {
      if (changed) s_flag = 1;                   // benign race: all write 1
      __syncthreads();                           // B2 (check iters only)
      if (s_flag == 0) break;                    // no change at iter itr -> identity
      changed = false;
    }
  }

  // writeback inner 96x64 from registers (coalesced 16B stores)
  if (tx >= 4 && tx <= 27 && gc < 512) {
    float* obase = dst + img * NPIMG;
#pragma unroll
    for (int r = 0; r < SROWS; ++r) {
      int er = sy * SROWS + r;
      if (er >= HALO && er < HALO + TILE_H)
        *(float4*)(obase + (gr0 + r) * 512 + gc) = cur[r];
    }
  }
}

// ------- fused: contour image + per-label count/sums, float4 per thread -----
__global__ __launch_bounds__(256) void k_cimgcount(const float* __restrict__ V,
                                                   float* __restrict__ Cm,
                                                   u32* __restrict__ key, u32* __restrict__ cnt,
                                                   u32* __restrict__ sr, u32* __restrict__ sc) {
  __shared__ u32 hl[LH], hn[LH], hr[LH], hc2[LH];
  __shared__ u32 s_n, s_r, s_c;
  const int tid = threadIdx.x;
  for (int e = tid; e < LH; e += 256) { hl[e] = 0; hn[e] = 0; hr[e] = 0; hc2[e] = 0; }
  if (tid == 0) { s_n = 0; s_r = 0; s_c = 0; }
  __syncthreads();
  int i4 = blockIdx.x * 256 + tid;               // grid exact: NPIXC/4/256
  int img = i4 >> 16, q4 = i4 & 65535;           // 65536 float4 per image
  int r = q4 >> 7, c = (q4 & 127) << 2;          // row, first column of 4
  const float* base = V + img * NPIMG;
  const float4 zero4 = make_float4(0.f, 0.f, 0.f, 0.f);
  float4 M = *(const float4*)(base + r * 512 + c);
  float4 out = zero4;
  if (M.x > 0.f || M.y > 0.f || M.z > 0.f || M.w > 0.f) {
    float4 U = (r > 0)   ? *(const float4*)(base + (r - 1) * 512 + c) : zero4;
    float4 D = (r < 511) ? *(const float4*)(base + (r + 1) * 512 + c) : zero4;
    float UL = (r > 0 && c > 0)       ? base[(r - 1) * 512 + c - 1] : 0.f;
    float UR = (r > 0 && c < 508)     ? base[(r - 1) * 512 + c + 4] : 0.f;
    float ML = (c > 0)                ? base[r * 512 + c - 1]       : 0.f;
    float MR = (c < 508)              ? base[r * 512 + c + 4]       : 0.f;
    float DL = (r < 511 && c > 0)     ? base[(r + 1) * 512 + c - 1] : 0.f;
    float DR = (r < 511 && c < 508)   ? base[(r + 1) * 512 + c + 4] : 0.f;
    float4 mn;
    mn.x = fminf(fminf(fminf(UL, U.x), fminf(U.y, ML)),
                 fminf(fminf(M.y, DL), fminf(D.x, D.y)));
    mn.y = fminf(fminf(fminf(U.x, U.y), fminf(U.z, M.x)),
                 fminf(fminf(M.z, D.x), fminf(D.y, D.z)));
    mn.z = fminf(fminf(fminf(U.y, U.z), fminf(U.w, M.y)),
                 fminf(fminf(M.w, D.y), fminf(D.z, D.w)));
    mn.w = fminf(fminf(fminf(U.z, U.w), fminf(UR, M.z)),
                 fminf(fminf(MR, D.z), fminf(D.w, DR)));
    out.x = (M.x > 0.f && mn.x == 0.f) ? M.x : 0.f;
    out.y = (M.y > 0.f && mn.y == 0.f) ? M.y : 0.f;
    out.z = (M.z > 0.f && mn.z == 0.f) ? M.z : 0.f;
    out.w = (M.w > 0.f && mn.w == 0.f) ? M.w : 0.f;
  }
  *(float4*)(Cm + img * NPIMG + r * 512 + c) = out;
  // stats for nonzero contour pixels; per-thread partials -> <=1 totals add
  u32 tn = 0, tr = 0, tc = 0;
#pragma unroll
  for (int comp = 0; comp < 4; ++comp) {
    float ov = (comp == 0) ? out.x : (comp == 1) ? out.y : (comp == 2) ? out.z : out.w;
    if (ov == 0.f) continue;
    u32 L = (u32)ov;
    u32 cc = (u32)(c + comp);
    u32 h = hashS(L);
    bool ins = false;
    for (u32 pr = 0; pr < LH; ++pr) {
      u32 e = (h + pr) & (LH - 1);
      u32 k = atomicCAS(&hl[e], 0u, L);
      if (k == 0u || k == L) {
        atomicAdd(&hn[e], 1u); atomicAdd(&hr[e], (u32)r); atomicAdd(&hc2[e], cc);
        ins = true; break;
      }
    }
    if (!ins) {  // overflow fallback: direct global path
      u32 hg = hashL(L), slot = 0xFFFFFFFFu;
      for (u32 pr = 0; pr < CAP; ++pr) {
        u32 k = key[img * CAP + hg];
        if (k == L) { slot = hg; break; }
        if (k == 0u) {
          u32 old = atomicCAS(&key[img * CAP + hg], 0u, L);
          if (old == 0u || old == L) { slot = hg; break; }
        }
        hg = (hg + 1) & (CAP - 1);
      }
      if (slot != 0xFFFFFFFFu) {
        u32 s = (u32)img * NSLOT + slot;
        atomicAdd(&cnt[s], 1u); atomicAdd(&sr[s], (u32)r); atomicAdd(&sc[s], cc);
      }
    }
    tn += 1u; tr += (u32)r; tc += cc;
  }
  if (tn) { atomicAdd(&s_n, tn); atomicAdd(&s_r, tr); atomicAdd(&s_c, tc); }
  __syncthreads();
  // flush LDS table: one global probe + 3 atomics per distinct label
  int im = (blockIdx.x * 256) >> 16;             // whole block is in one image
  for (int e = tid; e < LH; e += 256) {
    u32 L = hl[e];
    if (L == 0u) continue;
    u32 hg = hashL(L), slot = 0xFFFFFFFFu;
    for (u32 pr = 0; pr < CAP; ++pr) {
      u32 k = key[im * CAP + hg];
      if (k == L) { slot = hg; break; }
      if (k == 0u) {
        u32 old = atomicCAS(&key[im * CAP + hg], 0u, L);
        if (old == 0u || old == L) { slot = hg; break; }
      }
      hg = (hg + 1) & (CAP - 1);
    }
    if (slot != 0xFFFFFFFFu) {
      u32 s = (u32)im * NSLOT + slot;
      atomicAdd(&cnt[s], hn[e]); atomicAdd(&sr[s], hr[e]); atomicAdd(&sc[s], hc2[e]);
    }
  }
  if (tid == 0 && s_n) {
    u32 s = (u32)im * NSLOT + SLOT0;
    atomicAdd(&cnt[s], s_n); atomicAdd(&sr[s], s_r); atomicAdd(&sc[s], s_c);
  }
}

// ------- compact occupied hash slots (+label 0) into dense per-image lists --
__global__ __launch_bounds__(256) void k_compact(const u32* __restrict__ key,
                                                 const u32* __restrict__ cnt,
                                                 const u32* __restrict__ sr, const u32* __restrict__ sc,
                                                 u32* __restrict__ nlab, u32* __restrict__ labD,
                                                 u32* __restrict__ cntD, u32* __restrict__ srD,
                                                 u32* __restrict__ scD, u32* __restrict__ slotD) {
  int i = blockIdx.x * 256 + threadIdx.x;
  if (i >= NDN) return;
  int img = i / NSLOT, s = i - img * NSLOT;
  u32 L, n, a, b2;
  if (s < (int)CAP) {
    L = key[img * CAP + s];
    if (L == 0u) return;
    n = cnt[img * NSLOT + s];
    a = sr[img * NSLOT + s]; b2 = sc[img * NSLOT + s];
  } else {
    u32 nn = cnt[img * NSLOT + SLOT0];
    n = NPIMG - nn;                     // label-0 (background) pixel count
    if (n == 0u) return;
    L = 0u;
    a = TOTR - sr[img * NSLOT + SLOT0]; b2 = TOTR - sc[img * NSLOT + SLOT0];
  }
  u32 j = atomicAdd(&nlab[img], 1u);
  if (j < MAXL) {
    labD[img * MAXL + j] = L; cntD[img * MAXL + j] = n;
    srD[img * MAXL + j] = a;  scD[img * MAXL + j] = b2;
    slotD[img * MAXL + j] = (u32)s;
  }
}

// ---------------- pass 2: per-label min encoded angle (LDS slot agg) --------
__global__ __launch_bounds__(256) void k_angle(const float* __restrict__ Cm,
                                               const u32* __restrict__ key, const u32* __restrict__ cnt,
                                               const u32* __restrict__ sr, const u32* __restrict__ sc,
                                               u64* __restrict__ amin) {
  __shared__ u32 asl[LH];
  __shared__ u64 amn[LH];
  __shared__ u64 wmin[4];
  const int tid = threadIdx.x;
  for (int e = tid; e < LH; e += 256) { asl[e] = 0; amn[e] = ~0ull; }
  __syncthreads();
  int i = blockIdx.x * 256 + tid;
  int img = i >> 18, q = i & (NPIMG - 1);
  int r = q >> 9, c = q & 511;
  float v = Cm[i];
  u64 e0 = ~0ull;
  if (v == 0.f) {
    u32 base = (u32)img * NSLOT + SLOT0;
    u32 n0 = NPIMG - cnt[base];                   // >=1 since this pixel is zero
    double cr = (double)(TOTR - sr[base]) / (double)n0;
    double cc = (double)(TOTR - sc[base]) / (double)n0;
    e0 = encAng(atan2((double)c - cc, (double)r - cr));
  } else {
    u32 L = (u32)v;
    u32 h = hashL(L);
    for (u32 pr = 0; pr < CAP && key[img * CAP + h] != L; ++pr) h = (h + 1) & (CAP - 1);
    u32 s = (u32)img * NSLOT + h;
    u32 n = cnt[s];
    double cr = (double)sr[s] / (double)n;
    double cc = (double)sc[s] / (double)n;
    u64 enc = encAng(atan2((double)c - cc, (double)r - cr));
    u32 kk = h + 1, hh = hashS(kk);
    bool ins = false;
    for (u32 pr = 0; pr < LH; ++pr) {
      u32 e = (hh + pr) & (LH - 1);
      u32 k = atomicCAS(&asl[e], 0u, kk);
      if (k == 0u || k == kk) { atomicMin(&amn[e], enc); ins = true; break; }
    }
    if (!ins) atomicMin(&amin[s], enc);
  }
  // block-reduce the hot label-0 slot to 1 atomic/block
  for (int o = 32; o > 0; o >>= 1) {
    u64 other = __shfl_xor(e0, o, 64);
    e0 = other < e0 ? other : e0;
  }
  int lane = tid & 63, wid = tid >> 6;
  if (lane == 0) wmin[wid] = e0;
  __syncthreads();
  int im = (blockIdx.x * 256) >> 18;
  if (tid == 0) {
    u64 m = wmin[0];
    for (int k = 1; k < 4; ++k) m = wmin[k] < m ? wmin[k] : m;
    if (m != ~0ull) atomicMin(&amin[(u32)im * NSLOT + SLOT0], m);
  }
  for (int e = tid; e < LH; e += 256)
    if (asl[e]) atomicMin(&amin[(u32)im * NSLOT + (asl[e] - 1)], amn[e]);
}

// ---------------- pass 3: min row-major index among min-angle points --------
__global__ __launch_bounds__(256) void k_idx(const float* __restrict__ Cm,
                                             const u32* __restrict__ key, const u32* __restrict__ cnt,
                                             const u32* __restrict__ sr, const u32* __restrict__ sc,
                                             const u64* __restrict__ amin, u32* __restrict__ imin) {
  __shared__ u32 isl[LH];
  __shared__ u32 imn[LH];
  const int tid = threadIdx.x;
  for (int e = tid; e < LH; e += 256) { isl[e] = 0; imn[e] = 0xFFFFFFFFu; }
  __syncthreads();
  int i = blockIdx.x * 256 + tid;
  int img = i >> 18, q = i & (NPIMG - 1);
  int r = q >> 9, c = q & 511;
  float v = Cm[i];
  u32 sl; double cr, cc;
  if (v == 0.f) {
    sl = SLOT0;
    u32 s = (u32)img * NSLOT + SLOT0;
    u32 n0 = NPIMG - cnt[s];
    cr = (double)(TOTR - sr[s]) / (double)n0;
    cc = (double)(TOTR - sc[s]) / (double)n0;
  } else {
    u32 L = (u32)v;
    u32 h = hashL(L);
    for (u32 pr = 0; pr < CAP && key[img * CAP + h] != L; ++pr) h = (h + 1) & (CAP - 1);
    sl = h;
    u32 s = (u32)img * NSLOT + h;
    u32 n = cnt[s];
    cr = (double)sr[s] / (double)n;
    cc = (double)sc[s] / (double)n;
  }
  u64 e = encAng(atan2((double)c - cc, (double)r - cr));
  if (e == amin[(u32)img * NSLOT + sl]) {
    u32 kk = sl + 1, hh = hashS(kk);
    bool ins = false;
    for (u32 pr = 0; pr < LH; ++pr) {
      u32 e2 = (hh + pr) & (LH - 1);
      u32 k = atomicCAS(&isl[e2], 0u, kk);
      if (k == 0u || k == kk) { atomicMin(&imn[e2], (u32)q); ins = true; break; }
    }
    if (!ins) atomicMin(&imin[(u32)img * NSLOT + sl], (u32)q);
  }
  __syncthreads();
  int im = (blockIdx.x * 256) >> 18;
  for (int e2 = tid; e2 < LH; e2 += 256)
    if (isl[e2]) atomicMin(&imin[(u32)im * NSLOT + (isl[e2] - 1)], imn[e2]);
}

// ------- gather dense lists, parallel rank-sort, parallel match -------------
__global__ __launch_bounds__(256) void k_match(const u32* __restrict__ nlab,
                                               const u32* __restrict__ labD, const u32* __restrict__ cntD,
                                               const u32* __restrict__ srD, const u32* __restrict__ scD,
                                               const u32* __restrict__ slotD, const u32* __restrict__ imin,
                                               const float* __restrict__ wp, float* __restrict__ out) {
  __shared__ u32 lbl[2][MAXL];
  __shared__ double cx[2][MAXL], cy[2][MAXL], Rr[2][MAXL];
  __shared__ int nlist[2];
  __shared__ double wsum[4];
  const int tid = threadIdx.x;
  double S = 0.0;                        // per-thread partial
  for (int b = 0; b < BN; ++b) {
    __syncthreads();
    if (tid == 0) { nlist[0] = nlist[1] = 0; }
    __syncthreads();
    int tot[2];
    for (int f = 0; f < 2; ++f) {
      int t = f * BN + b;
      int ntot = (int)nlab[t];
      tot[f] = ntot;                     // unique-label count (pre-MIN_PTS)
      int nl = ntot > MAXL ? MAXL : ntot;
      for (int s2 = tid; s2 < nl; s2 += 256) {
        u32 n = cntD[t * MAXL + s2];
        if (n < 10u) continue;
        int j = atomicAdd(&nlist[f], 1); // j < MAXL guaranteed
        lbl[f][j] = labD[t * MAXL + s2];
        cx[f][j] = (double)srD[t * MAXL + s2] / (double)n;
        cy[f][j] = (double)scD[t * MAXL + s2] / (double)n;
        u32 pi = imin[t * NSLOT + slotD[t * MAXL + s2]];
        double r0 = (double)(pi >> 9), c0 = (double)(pi & 511u);
        Rr[f][j] = sqrt(r0 * r0 + c0 * c0);
      }
    }
    __syncthreads();
    int np = nlist[0], nt = nlist[1];
    bool valid = (tot[0] >= 2) && (np >= 1) && (tot[1] >= 2) && (nt >= 1);
    if (valid) {
      // parallel rank sort (labels unique -> rank is a permutation)
      u32 ml[2][2]; double mx[2][2], my[2][2], mr[2][2]; int rk[2][2]; int nh[2];
      for (int f = 0; f < 2; ++f) {
        int n = f ? nt : np;
        nh[f] = 0;
        for (int i = tid; i < n; i += 256) {
          int k = nh[f]++;
          u32 L = lbl[f][i];
          ml[f][k] = L; mx[f][k] = cx[f][i]; my[f][k] = cy[f][i]; mr[f][k] = Rr[f][i];
          int rr = 0;
          for (int j = 0; j < n; ++j) rr += (lbl[f][j] < L) ? 1 : 0;
          rk[f][k] = rr;
        }
      }
      __syncthreads();
      for (int f = 0; f < 2; ++f)
        for (int k = 0; k < nh[f]; ++k) {
          int rr = rk[f][k];
          lbl[f][rr] = ml[f][k]; cx[f][rr] = mx[f][k];
          cy[f][rr] = my[f][k];  Rr[f][rr] = mr[f][k];
        }
      __syncthreads();
      // parallel nearest-center match over rows of the smaller list
      if (nt <= np) {
        for (int j = tid; j < nt; j += 256) {
          int m = 0; double bd = 1e300;
          double tx0 = cx[1][j], ty0 = cy[1][j];
          for (int i2 = 0; i2 < np; ++i2) {
            double dx = tx0 - cx[0][i2], dy = ty0 - cy[0][i2];
            double d = dx * dx + dy * dy;
            if (d < bd) { bd = d; m = i2; }
          }
          S += fabs(Rr[0][m] - Rr[1][j]);
        }
      } else {
        for (int i2 = tid; i2 < np; i2 += 256) {
          int m = 0; double bd = 1e300;
          double px0 = cx[0][i2], py0 = cy[0][i2];
          for (int j = 0; j < nt; ++j) {
            double dx = px0 - cx[1][j], dy = py0 - cy[1][j];
            double d = dx * dx + dy * dy;
            if (d < bd) { bd = d; m = j; }
          }
          S += fabs(Rr[1][m] - Rr[0][i2]);
        }
      }
    }
  }
  // block-reduce per-thread partials
  for (int o = 32; o > 0; o >>= 1) S += __shfl_xor(S, o, 64);
  int lane = tid & 63, wid = tid >> 6;
  if (lane == 0) wsum[wid] = S;
  __syncthreads();
  if (tid == 0) {
    double total = wsum[0] + wsum[1] + wsum[2] + wsum[3];
    total *= (1.5 / 3.14159265358979323846);   // sum_k 1/(k*pi), k=1,2
    float w = wp[0];
    out[0] = (float)total * (0.5f * w * w);
  }
}

extern "C" void kernel_launch(void* const* d_in, const int* in_sizes, int n_in,
                              void* d_out, int out_size, void* d_ws, size_t ws_size,
                              hipStream_t stream) {
  const float* pred = (const float*)d_in[0];
  const float* tgt  = (const float*)d_in[1];
  const float* wp   = (const float*)d_in[2];
  float* out = (float*)d_out;

  char* ws = (char*)d_ws;
  size_t off = 0;
  float* A  = (float*)(ws + off); off += (size_t)NPIXC * 4;
  float* Bb = (float*)(ws + off); off += (size_t)NPIXC * 4;
  u32* key  = (u32*)(ws + off);   off += (size_t)NIMG * CAP * 4;
  u32* cnt  = (u32*)(ws + off);   off += (size_t)NIMG * NSLOT * 4;
  u32* sr   = (u32*)(ws + off);   off += (size_t)NIMG * NSLOT * 4;
  u32* sc   = (u32*)(ws + off);   off += (size_t)NIMG * NSLOT * 4;
  u64* amin = (u64*)(ws + off);   off += (size_t)NIMG * NSLOT * 8;
  u32* imin = (u32*)(ws + off);   off += (size_t)NIMG * NSLOT * 4;
  u32* nlab = (u32*)(ws + off);   off += (size_t)NIMG * 4;
  u32* labD = (u32*)(ws + off);   off += (size_t)NIMG * MAXL * 4;
  u32* cntD = (u32*)(ws + off);   off += (size_t)NIMG * MAXL * 4;
  u32* srD  = (u32*)(ws + off);   off += (size_t)NIMG * MAXL * 4;
  u32* scD  = (u32*)(ws + off);   off += (size_t)NIMG * MAXL * 4;
  u32* slotD= (u32*)(ws + off);   off += (size_t)NIMG * MAXL * 4;

  size_t zlen = (size_t)NIMG * CAP * 4 + 3ull * NIMG * NSLOT * 4;
  hipMemsetAsync(key, 0, zlen, stream);
  hipMemsetAsync(amin, 0xFF, (size_t)NIMG * NSLOT * 12, stream);
  hipMemsetAsync(nlab, 0, (size_t)NIMG * 4, stream);

  const int gC = NPIXC / 256;            // exact (k_angle/k_idx grids)
  const int gC4 = NPIXC / 4 / 256;       // float4 cimgcount grid
  const int gS = (NDN + 255) / 256;      // slot-compaction grid

  // first launch fuses init (labels from pred/tgt) with 16 prop iterations
  k_prop<<<PROPBLOCKS, 256, 0, stream>>>(A, A, pred, tgt, HALO, 1);
  float* src = A; float* dst = Bb;
  int done = HALO;
  while (done < PROP_ITERS) {
    int k = PROP_ITERS - done; if (k > HALO) k = HALO;
    k_prop<<<PROPBLOCKS, 256, 0, stream>>>(src, dst, pred, tgt, k, 0);
    float* t2 = src; src = dst; dst = t2;
    done += k;
  }
  float* Cm = dst;                       // spare buffer holds contour image
  k_cimgcount<<<gC4, 256, 0, stream>>>(src, Cm, key, cnt, sr, sc);
  k_compact<<<gS, 256, 0, stream>>>(key, cnt, sr, sc, nlab, labD, cntD, srD, scD, slotD);
  k_angle<<<gC, 256, 0, stream>>>(Cm, key, cnt, sr, sc, amin);
  k_idx<<<gC, 256, 0, stream>>>(Cm, key, cnt, sr, sc, amin, imin);
  k_match<<<1, 256, 0, stream>>>(nlab, labD, cntD, srD, scD, slotD, imin, wp, out);
}

// Round 14
// 1407.294 us; speedup vs baseline: 2.1816x; 1.0371x over previous
//
#include <hip/hip_runtime.h>

typedef unsigned int u32;
typedef unsigned long long u64;

#define BN 8
#define NIMG 16                 // 2 fields (pred,tgt) * 8 batch
#define NPIMG (512*512)
#define NPIXC (NIMG*NPIMG)      // 4,194,304
#define PP (514*514)            // padded pixels per image (for label values)
#define CAP 8192u               // hash capacity per image-field (pow2)
#define SLOT0 8192
#define NSLOT 8193
#define NDN (NIMG*NSLOT)
#define TOTR 66977792u          // sum of row (=col) index over 512x512 (exact)
#define MAXL 512
#define PROP_ITERS 500
#define LH 64                   // per-block LDS label-hash entries (pow2)

// ---- tiled propagation: output 96x64, ext 128x96, 16 iters/launch ---------
// 6x8 tiles/image -> 768 blocks = exactly 3 blocks/CU on 256 CUs.
#define TILE_W 96
#define TILE_H 64
#define HALO 16
#define CF4 32                  // 128/4 float4 cols = one 32-lane row group
#define NSTRIP 8                // strips of 12 rows (ext height 96)
#define SROWS 12
#define TPC 6
#define TPR 8
#define TPT (TPR*TPC)           // 48 tiles per image
#define PROPBLOCKS (NIMG*TPT)   // 768

__device__ __forceinline__ u32 hashL(u32 L) { return (L * 2654435761u) >> 19; }
__device__ __forceinline__ u32 hashS(u32 L) { return (L * 2654435761u) >> 26; }

// monotone map double -> u64 so unsigned min == double min
__device__ __forceinline__ u64 encAng(double a) {
  u64 u = (u64)__double_as_longlong(a);
  return (u >> 63) ? ~u : (u | 0x8000000000000000ull);
}

__device__ __forceinline__ float fmax3(float a, float b, float c) {
  return fmaxf(a, fmaxf(b, c));
}

// horizontal 3-max within a 32-lane row group; tile-edge cells forced 0
// (halo-invalid; contamination ring stays outside the inner output tile)
__device__ __forceinline__ float4 horizf4(float4 M, int tx) {
  float Lw = __shfl_up(M.w, 1);
  float Rx = __shfl_down(M.x, 1);
  if (tx == 0) Lw = 0.f;
  if (tx == CF4 - 1) Rx = 0.f;
  float4 hh;
  hh.x = fmax3(Lw, M.x, M.y);
  hh.y = fmax3(M.x, M.y, M.z);
  hh.z = fmax3(M.y, M.z, M.w);
  hh.w = fmax3(M.z, M.w, Rx);
  return hh;
}

// init label value for a float4 cell at (gr, gc) of image-field img
__device__ __forceinline__ float4 initVal(const float* __restrict__ pred,
                                          const float* __restrict__ tgt,
                                          int img, int gr, int gc) {
  const int f = img >> 3, b = img & 7;
  const float* fb = (f == 0 ? pred : tgt) + b * NPIMG;
  float4 x = *(const float4*)(fb + gr * 512 + gc);
  float lb = (float)(b * PP + (gr + 1) * 514 + (gc + 1));
  bool mx, my, mz, mw;
  if (f == 0) { mx = x.x > 0.f; my = x.y > 0.f; mz = x.z > 0.f; mw = x.w > 0.f; }
  else        { mx = x.x == 1.f; my = x.y == 1.f; mz = x.z == 1.f; mw = x.w == 1.f; }
  float4 v;
  v.x = mx ? lb : 0.f;
  v.y = my ? lb + 1.f : 0.f;
  v.z = mz ? lb + 2.f : 0.f;
  v.w = mw ? lb + 3.f : 0.f;
  return v;
}

// ---------------- k iterations of masked 3x3 max, register strips -----------
__global__ __launch_bounds__(256) void k_prop(const float* __restrict__ src,
                                              float* __restrict__ dst,
                                              const float* __restrict__ pred,
                                              const float* __restrict__ tgt,
                                              int niter, int first) {
  __shared__ float4 hTopS[2][NSTRIP][CF4];   // h row 0 of each strip
  __shared__ float4 hBotS[2][NSTRIP][CF4];   // h row SROWS-1 of each strip
  __shared__ int s_flag;
  const int tid = threadIdx.x;
  const int bx = blockIdx.x;
  // XCD-aware decode: bx&7 -> image pair (round-robin block->XCD heuristic)
  const int j = bx >> 3;
  const int img = ((bx & 7) << 1) + (j >= TPT ? 1 : 0);
  const int tt = (j >= TPT) ? (j - TPT) : j;
  const int tyT = tt / TPC, txT = tt % TPC;
  const int tx = tid & 31, sy = tid >> 5;
  const int gr0 = tyT * TILE_H - HALO + sy * SROWS;
  const int gc = txT * TILE_W - HALO + tx * 4;     // float4 fully in or out
  const bool gcok = (gc >= 0 && gc < 512);

  float4 cur[SROWS];
  if (first) {
#pragma unroll
    for (int r = 0; r < SROWS; ++r) {
      float4 v = make_float4(0.f, 0.f, 0.f, 0.f);
      int gr = gr0 + r;
      if (gcok && gr >= 0 && gr < 512)
        v = initVal(pred, tgt, img, gr, gc);
      cur[r] = v;
    }
  } else {
    const float* ibase = src + img * NPIMG;
#pragma unroll
    for (int r = 0; r < SROWS; ++r) {
      float4 v = make_float4(0.f, 0.f, 0.f, 0.f);
      int gr = gr0 + r;
      if (gcok && gr >= 0 && gr < 512)
        v = *(const float4*)(ibase + gr * 512 + gc);
      cur[r] = v;
    }
  }

  bool changed = false;
  for (int itr = 0; itr < niter; ++itr) {
    const int p = itr & 1;
    const bool chk = ((itr & 3) == 3);           // fixpoint test every 4 iters
    float4 h[SROWS];
#pragma unroll
    for (int r = 0; r < SROWS; ++r) h[r] = horizf4(cur[r], tx);
    hTopS[p][sy][tx] = h[0];
    hBotS[p][sy][tx] = h[SROWS - 1];
    if (chk && tid == 0) s_flag = 0;             // finalized before B1
    __syncthreads();                             // B1
    float4 zero = make_float4(0.f, 0.f, 0.f, 0.f);
    float4 hm = (sy > 0) ? hBotS[p][sy - 1][tx] : zero;
    float4 below = (sy < NSTRIP - 1) ? hTopS[p][sy + 1][tx] : zero;
#pragma unroll
    for (int r = 0; r < SROWS; ++r) {
      float4 hc = h[r];
      float4 hp = (r == SROWS - 1) ? below : h[r + 1];
      float4 o = cur[r], v;
      v.x = (o.x > 0.f) ? fmax3(hm.x, hc.x, hp.x) : 0.f;
      v.y = (o.y > 0.f) ? fmax3(hm.y, hc.y, hp.y) : 0.f;
      v.z = (o.z > 0.f) ? fmax3(hm.z, hc.z, hp.z) : 0.f;
      v.w = (o.w > 0.f) ? fmax3(hm.w, hc.w, hp.w) : 0.f;
      if (chk)
        changed = changed || (v.x != o.x) || (v.y != o.y) || (v.z != o.z) || (v.w != o.w);
      cur[r] = v;
      hm = hc;
    }
    if (chk) {
      if (changed) s_flag = 1;                   // benign race: all write 1
      __syncthreads();                           // B2 (check iters only)
      if (s_flag == 0) break;                    // no change at iter itr -> identity
      changed = false;
    }
  }

  // writeback inner 96x64 from registers (coalesced 16B stores)
  if (tx >= 4 && tx <= 27 && gc < 512) {
    float* obase = dst + img * NPIMG;
#pragma unroll
    for (int r = 0; r < SROWS; ++r) {
      int er = sy * SROWS + r;
      if (er >= HALO && er < HALO + TILE_H)
        *(float4*)(obase + (gr0 + r) * 512 + gc) = cur[r];
    }
  }
}

// ------- fused: contour image + per-label count/sums, float4 per thread -----
__global__ __launch_bounds__(256) void k_cimgcount(const float* __restrict__ V,
                                                   float* __restrict__ Cm,
                                                   u32* __restrict__ key, u32* __restrict__ cnt,
                                                   u32* __restrict__ sr, u32* __restrict__ sc) {
  __shared__ u32 hl[LH], hn[LH], hr[LH], hc2[LH];
  __shared__ u32 s_n, s_r, s_c;
  const int tid = threadIdx.x;
  for (int e = tid; e < LH; e += 256) { hl[e] = 0; hn[e] = 0; hr[e] = 0; hc2[e] = 0; }
  if (tid == 0) { s_n = 0; s_r = 0; s_c = 0; }
  __syncthreads();
  int i4 = blockIdx.x * 256 + tid;               // grid exact: NPIXC/4/256
  int img = i4 >> 16, q4 = i4 & 65535;           // 65536 float4 per image
  int r = q4 >> 7, c = (q4 & 127) << 2;          // row, first column of 4
  const float* base = V + img * NPIMG;
  const float4 zero4 = make_float4(0.f, 0.f, 0.f, 0.f);
  float4 M = *(const float4*)(base + r * 512 + c);
  float4 out = zero4;
  if (M.x > 0.f || M.y > 0.f || M.z > 0.f || M.w > 0.f) {
    float4 U = (r > 0)   ? *(const float4*)(base + (r - 1) * 512 + c) : zero4;
    float4 D = (r < 511) ? *(const float4*)(base + (r + 1) * 512 + c) : zero4;
    float UL = (r > 0 && c > 0)       ? base[(r - 1) * 512 + c - 1] : 0.f;
    float UR = (r > 0 && c < 508)     ? base[(r - 1) * 512 + c + 4] : 0.f;
    float ML = (c > 0)                ? base[r * 512 + c - 1]       : 0.f;
    float MR = (c < 508)              ? base[r * 512 + c + 4]       : 0.f;
    float DL = (r < 511 && c > 0)     ? base[(r + 1) * 512 + c - 1] : 0.f;
    float DR = (r < 511 && c < 508)   ? base[(r + 1) * 512 + c + 4] : 0.f;
    float4 mn;
    mn.x = fminf(fminf(fminf(UL, U.x), fminf(U.y, ML)),
                 fminf(fminf(M.y, DL), fminf(D.x, D.y)));
    mn.y = fminf(fminf(fminf(U.x, U.y), fminf(U.z, M.x)),
                 fminf(fminf(M.z, D.x), fminf(D.y, D.z)));
    mn.z = fminf(fminf(fminf(U.y, U.z), fminf(U.w, M.y)),
                 fminf(fminf(M.w, D.y), fminf(D.z, D.w)));
    mn.w = fminf(fminf(fminf(U.z, U.w), fminf(UR, M.z)),
                 fminf(fminf(MR, D.z), fminf(D.w, DR)));
    out.x = (M.x > 0.f && mn.x == 0.f) ? M.x : 0.f;
    out.y = (M.y > 0.f && mn.y == 0.f) ? M.y : 0.f;
    out.z = (M.z > 0.f && mn.z == 0.f) ? M.z : 0.f;
    out.w = (M.w > 0.f && mn.w == 0.f) ? M.w : 0.f;
  }
  *(float4*)(Cm + img * NPIMG + r * 512 + c) = out;
  // stats for nonzero contour pixels; per-thread partials -> <=1 totals add
  u32 tn = 0, tr = 0, tc = 0;
#pragma unroll
  for (int comp = 0; comp < 4; ++comp) {
    float ov = (comp == 0) ? out.x : (comp == 1) ? out.y : (comp == 2) ? out.z : out.w;
    if (ov == 0.f) continue;
    u32 L = (u32)ov;
    u32 cc = (u32)(c + comp);
    u32 h = hashS(L);
    bool ins = false;
    for (u32 pr = 0; pr < LH; ++pr) {
      u32 e = (h + pr) & (LH - 1);
      u32 k = atomicCAS(&hl[e], 0u, L);
      if (k == 0u || k == L) {
        atomicAdd(&hn[e], 1u); atomicAdd(&hr[e], (u32)r); atomicAdd(&hc2[e], cc);
        ins = true; break;
      }
    }
    if (!ins) {  // overflow fallback: direct global path
      u32 hg = hashL(L), slot = 0xFFFFFFFFu;
      for (u32 pr = 0; pr < CAP; ++pr) {
        u32 k = key[img * CAP + hg];
        if (k == L) { slot = hg; break; }
        if (k == 0u) {
          u32 old = atomicCAS(&key[img * CAP + hg], 0u, L);
          if (old == 0u || old == L) { slot = hg; break; }
        }
        hg = (hg + 1) & (CAP - 1);
      }
      if (slot != 0xFFFFFFFFu) {
        u32 s = (u32)img * NSLOT + slot;
        atomicAdd(&cnt[s], 1u); atomicAdd(&sr[s], (u32)r); atomicAdd(&sc[s], cc);
      }
    }
    tn += 1u; tr += (u32)r; tc += cc;
  }
  if (tn) { atomicAdd(&s_n, tn); atomicAdd(&s_r, tr); atomicAdd(&s_c, tc); }
  __syncthreads();
  // flush LDS table: one global probe + 3 atomics per distinct label
  int im = (blockIdx.x * 256) >> 16;             // whole block is in one image
  for (int e = tid; e < LH; e += 256) {
    u32 L = hl[e];
    if (L == 0u) continue;
    u32 hg = hashL(L), slot = 0xFFFFFFFFu;
    for (u32 pr = 0; pr < CAP; ++pr) {
      u32 k = key[im * CAP + hg];
      if (k == L) { slot = hg; break; }
      if (k == 0u) {
        u32 old = atomicCAS(&key[im * CAP + hg], 0u, L);
        if (old == 0u || old == L) { slot = hg; break; }
      }
      hg = (hg + 1) & (CAP - 1);
    }
    if (slot != 0xFFFFFFFFu) {
      u32 s = (u32)im * NSLOT + slot;
      atomicAdd(&cnt[s], hn[e]); atomicAdd(&sr[s], hr[e]); atomicAdd(&sc[s], hc2[e]);
    }
  }
  if (tid == 0 && s_n) {
    u32 s = (u32)im * NSLOT + SLOT0;
    atomicAdd(&cnt[s], s_n); atomicAdd(&sr[s], s_r); atomicAdd(&sc[s], s_c);
  }
}

// ------- compact occupied hash slots (+label 0) into dense per-image lists --
__global__ __launch_bounds__(256) void k_compact(const u32* __restrict__ key,
                                                 const u32* __restrict__ cnt,
                                                 const u32* __restrict__ sr, const u32* __restrict__ sc,
                                                 u32* __restrict__ nlab, u32* __restrict__ labD,
                                                 u32* __restrict__ cntD, u32* __restrict__ srD,
                                                 u32* __restrict__ scD, u32* __restrict__ slotD) {
  int i = blockIdx.x * 256 + threadIdx.x;
  if (i >= NDN) return;
  int img = i / NSLOT, s = i - img * NSLOT;
  u32 L, n, a, b2;
  if (s < (int)CAP) {
    L = key[img * CAP + s];
    if (L == 0u) return;
    n = cnt[img * NSLOT + s];
    a = sr[img * NSLOT + s]; b2 = sc[img * NSLOT + s];
  } else {
    u32 nn = cnt[img * NSLOT + SLOT0];
    n = NPIMG - nn;                     // label-0 (background) pixel count
    if (n == 0u) return;
    L = 0u;
    a = TOTR - sr[img * NSLOT + SLOT0]; b2 = TOTR - sc[img * NSLOT + SLOT0];
  }
  u32 j = atomicAdd(&nlab[img], 1u);
  if (j < MAXL) {
    labD[img * MAXL + j] = L; cntD[img * MAXL + j] = n;
    srD[img * MAXL + j] = a;  scD[img * MAXL + j] = b2;
    slotD[img * MAXL + j] = (u32)s;
  }
}

// -------- pass 2: per-label min encoded angle (LDS slot agg + enc cache) ----
__global__ __launch_bounds__(256) void k_angle(const float* __restrict__ Cm,
                                               const u32* __restrict__ key, const u32* __restrict__ cnt,
                                               const u32* __restrict__ sr, const u32* __restrict__ sc,
                                               u64* __restrict__ amin,
                                               u64* __restrict__ encB, int useEnc) {
  __shared__ u32 asl[LH];
  __shared__ u64 amn[LH];
  __shared__ u64 wmin[4];
  const int tid = threadIdx.x;
  for (int e = tid; e < LH; e += 256) { asl[e] = 0; amn[e] = ~0ull; }
  __syncthreads();
  int i = blockIdx.x * 256 + tid;
  int img = i >> 18, q = i & (NPIMG - 1);
  int r = q >> 9, c = q & 511;
  float v = Cm[i];
  u64 e0 = ~0ull;
  u64 myenc;
  if (v == 0.f) {
    u32 base = (u32)img * NSLOT + SLOT0;
    u32 n0 = NPIMG - cnt[base];                   // >=1 since this pixel is zero
    double cr = (double)(TOTR - sr[base]) / (double)n0;
    double cc = (double)(TOTR - sc[base]) / (double)n0;
    e0 = encAng(atan2((double)c - cc, (double)r - cr));
    myenc = e0;
  } else {
    u32 L = (u32)v;
    u32 h = hashL(L);
    for (u32 pr = 0; pr < CAP && key[img * CAP + h] != L; ++pr) h = (h + 1) & (CAP - 1);
    u32 s = (u32)img * NSLOT + h;
    u32 n = cnt[s];
    double cr = (double)sr[s] / (double)n;
    double cc = (double)sc[s] / (double)n;
    u64 enc = encAng(atan2((double)c - cc, (double)r - cr));
    myenc = enc;
    u32 kk = h + 1, hh = hashS(kk);
    bool ins = false;
    for (u32 pr = 0; pr < LH; ++pr) {
      u32 e = (hh + pr) & (LH - 1);
      u32 k = atomicCAS(&asl[e], 0u, kk);
      if (k == 0u || k == kk) { atomicMin(&amn[e], enc); ins = true; break; }
    }
    if (!ins) atomicMin(&amin[s], enc);
  }
  if (useEnc) encB[i] = myenc;                    // cache for k_idx
  // block-reduce the hot label-0 slot to 1 atomic/block
  for (int o = 32; o > 0; o >>= 1) {
    u64 other = __shfl_xor(e0, o, 64);
    e0 = other < e0 ? other : e0;
  }
  int lane = tid & 63, wid = tid >> 6;
  if (lane == 0) wmin[wid] = e0;
  __syncthreads();
  int im = (blockIdx.x * 256) >> 18;
  if (tid == 0) {
    u64 m = wmin[0];
    for (int k = 1; k < 4; ++k) m = wmin[k] < m ? wmin[k] : m;
    if (m != ~0ull) atomicMin(&amin[(u32)im * NSLOT + SLOT0], m);
  }
  for (int e = tid; e < LH; e += 256)
    if (asl[e]) atomicMin(&amin[(u32)im * NSLOT + (asl[e] - 1)], amn[e]);
}

// ---------------- pass 3: min row-major index among min-angle points --------
__global__ __launch_bounds__(256) void k_idx(const float* __restrict__ Cm,
                                             const u32* __restrict__ key, const u32* __restrict__ cnt,
                                             const u32* __restrict__ sr, const u32* __restrict__ sc,
                                             const u64* __restrict__ amin, u32* __restrict__ imin,
                                             const u64* __restrict__ encB, int useEnc) {
  __shared__ u32 isl[LH];
  __shared__ u32 imn[LH];
  const int tid = threadIdx.x;
  for (int e = tid; e < LH; e += 256) { isl[e] = 0; imn[e] = 0xFFFFFFFFu; }
  __syncthreads();
  int i = blockIdx.x * 256 + tid;
  int img = i >> 18, q = i & (NPIMG - 1);
  int r = q >> 9, c = q & 511;
  float v = Cm[i];
  u32 sl;
  u64 e;
  if (useEnc) {
    e = encB[i];                                  // exact cached encoding
    if (v == 0.f) sl = SLOT0;
    else {
      u32 L = (u32)v;
      u32 h = hashL(L);
      for (u32 pr = 0; pr < CAP && key[img * CAP + h] != L; ++pr) h = (h + 1) & (CAP - 1);
      sl = h;
    }
  } else {
    double cr, cc;
    if (v == 0.f) {
      sl = SLOT0;
      u32 s = (u32)img * NSLOT + SLOT0;
      u32 n0 = NPIMG - cnt[s];
      cr = (double)(TOTR - sr[s]) / (double)n0;
      cc = (double)(TOTR - sc[s]) / (double)n0;
    } else {
      u32 L = (u32)v;
      u32 h = hashL(L);
      for (u32 pr = 0; pr < CAP && key[img * CAP + h] != L; ++pr) h = (h + 1) & (CAP - 1);
      sl = h;
      u32 s = (u32)img * NSLOT + h;
      u32 n = cnt[s];
      cr = (double)sr[s] / (double)n;
      cc = (double)sc[s] / (double)n;
    }
    e = encAng(atan2((double)c - cc, (double)r - cr));
  }
  if (e == amin[(u32)img * NSLOT + sl]) {
    u32 kk = sl + 1, hh = hashS(kk);
    bool ins = false;
    for (u32 pr = 0; pr < LH; ++pr) {
      u32 e2 = (hh + pr) & (LH - 1);
      u32 k = atomicCAS(&isl[e2], 0u, kk);
      if (k == 0u || k == kk) { atomicMin(&imn[e2], (u32)q); ins = true; break; }
    }
    if (!ins) atomicMin(&imin[(u32)img * NSLOT + sl], (u32)q);
  }
  __syncthreads();
  int im = (blockIdx.x * 256) >> 18;
  for (int e2 = tid; e2 < LH; e2 += 256)
    if (isl[e2]) atomicMin(&imin[(u32)im * NSLOT + (isl[e2] - 1)], imn[e2]);
}

// ------- per-batch gather, rank-sort, match; 8 blocks, atomicAdd partials ---
__global__ __launch_bounds__(256) void k_match(const u32* __restrict__ nlab,
                                               const u32* __restrict__ labD, const u32* __restrict__ cntD,
                                               const u32* __restrict__ srD, const u32* __restrict__ scD,
                                               const u32* __restrict__ slotD, const u32* __restrict__ imin,
                                               const float* __restrict__ wp, float* __restrict__ out) {
  __shared__ u32 lbl[2][MAXL];
  __shared__ double cx[2][MAXL], cy[2][MAXL], Rr[2][MAXL];
  __shared__ int nlist[2];
  __shared__ double wsum[4];
  const int tid = threadIdx.x;
  const int b = blockIdx.x;              // batch index (grid = BN blocks)
  double S = 0.0;                        // per-thread partial
  if (tid == 0) { nlist[0] = nlist[1] = 0; }
  __syncthreads();
  int tot[2];
  for (int f = 0; f < 2; ++f) {
    int t = f * BN + b;
    int ntot = (int)nlab[t];
    tot[f] = ntot;                       // unique-label count (pre-MIN_PTS)
    int nl = ntot > MAXL ? MAXL : ntot;
    for (int s2 = tid; s2 < nl; s2 += 256) {
      u32 n = cntD[t * MAXL + s2];
      if (n < 10u) continue;
      int j = atomicAdd(&nlist[f], 1);   // j < MAXL guaranteed
      lbl[f][j] = labD[t * MAXL + s2];
      cx[f][j] = (double)srD[t * MAXL + s2] / (double)n;
      cy[f][j] = (double)scD[t * MAXL + s2] / (double)n;
      u32 pi = imin[t * NSLOT + slotD[t * MAXL + s2]];
      double r0 = (double)(pi >> 9), c0 = (double)(pi & 511u);
      Rr[f][j] = sqrt(r0 * r0 + c0 * c0);
    }
  }
  __syncthreads();
  int np = nlist[0], nt = nlist[1];
  bool valid = (tot[0] >= 2) && (np >= 1) && (tot[1] >= 2) && (nt >= 1);
  if (valid) {
    // parallel rank sort (labels unique -> rank is a permutation)
    u32 ml[2][2]; double mx[2][2], my[2][2], mr[2][2]; int rk[2][2]; int nh[2];
    for (int f = 0; f < 2; ++f) {
      int n = f ? nt : np;
      nh[f] = 0;
      for (int i = tid; i < n; i += 256) {
        int k = nh[f]++;
        u32 L = lbl[f][i];
        ml[f][k] = L; mx[f][k] = cx[f][i]; my[f][k] = cy[f][i]; mr[f][k] = Rr[f][i];
        int rr = 0;
        for (int j = 0; j < n; ++j) rr += (lbl[f][j] < L) ? 1 : 0;
        rk[f][k] = rr;
      }
    }
    __syncthreads();
    for (int f = 0; f < 2; ++f)
      for (int k = 0; k < nh[f]; ++k) {
        int rr = rk[f][k];
        lbl[f][rr] = ml[f][k]; cx[f][rr] = mx[f][k];
        cy[f][rr] = my[f][k];  Rr[f][rr] = mr[f][k];
      }
    __syncthreads();
    // parallel nearest-center match over rows of the smaller list
    if (nt <= np) {
      for (int j = tid; j < nt; j += 256) {
        int m = 0; double bd = 1e300;
        double tx0 = cx[1][j], ty0 = cy[1][j];
        for (int i2 = 0; i2 < np; ++i2) {
          double dx = tx0 - cx[0][i2], dy = ty0 - cy[0][i2];
          double d = dx * dx + dy * dy;
          if (d < bd) { bd = d; m = i2; }
        }
        S += fabs(Rr[0][m] - Rr[1][j]);
      }
    } else {
      for (int i2 = tid; i2 < np; i2 += 256) {
        int m = 0; double bd = 1e300;
        double px0 = cx[0][i2], py0 = cy[0][i2];
        for (int j = 0; j < nt; ++j) {
          double dx = px0 - cx[1][j], dy = py0 - cy[1][j];
          double d = dx * dx + dy * dy;
          if (d < bd) { bd = d; m = j; }
        }
        S += fabs(Rr[1][m] - Rr[0][i2]);
      }
    }
  }
  // block-reduce per-thread partials, then one atomicAdd per batch
  for (int o = 32; o > 0; o >>= 1) S += __shfl_xor(S, o, 64);
  int lane = tid & 63, wid = tid >> 6;
  if (lane == 0) wsum[wid] = S;
  __syncthreads();
  if (tid == 0) {
    double total = wsum[0] + wsum[1] + wsum[2] + wsum[3];
    total *= (1.5 / 3.14159265358979323846);   // sum_k 1/(k*pi), k=1,2
    float w = wp[0];
    atomicAdd(out, (float)total * (0.5f * w * w));
  }
}

extern "C" void kernel_launch(void* const* d_in, const int* in_sizes, int n_in,
                              void* d_out, int out_size, void* d_ws, size_t ws_size,
                              hipStream_t stream) {
  const float* pred = (const float*)d_in[0];
  const float* tgt  = (const float*)d_in[1];
  const float* wp   = (const float*)d_in[2];
  float* out = (float*)d_out;

  char* ws = (char*)d_ws;
  size_t off = 0;
  float* A  = (float*)(ws + off); off += (size_t)NPIXC * 4;
  float* Bb = (float*)(ws + off); off += (size_t)NPIXC * 4;
  u32* key  = (u32*)(ws + off);   off += (size_t)NIMG * CAP * 4;
  u32* cnt  = (u32*)(ws + off);   off += (size_t)NIMG * NSLOT * 4;
  u32* sr   = (u32*)(ws + off);   off += (size_t)NIMG * NSLOT * 4;
  u32* sc   = (u32*)(ws + off);   off += (size_t)NIMG * NSLOT * 4;
  u64* amin = (u64*)(ws + off);   off += (size_t)NIMG * NSLOT * 8;
  u32* imin = (u32*)(ws + off);   off += (size_t)NIMG * NSLOT * 4;
  u32* nlab = (u32*)(ws + off);   off += (size_t)NIMG * 4;
  u32* labD = (u32*)(ws + off);   off += (size_t)NIMG * MAXL * 4;
  u32* cntD = (u32*)(ws + off);   off += (size_t)NIMG * MAXL * 4;
  u32* srD  = (u32*)(ws + off);   off += (size_t)NIMG * MAXL * 4;
  u32* scD  = (u32*)(ws + off);   off += (size_t)NIMG * MAXL * 4;
  u32* slotD= (u32*)(ws + off);   off += (size_t)NIMG * MAXL * 4;
  // enc cache (optional, guarded by ws_size): 8B per pixel
  size_t offE = (off + 7) & ~(size_t)7;
  u64* encB = (u64*)(ws + offE);
  int useEnc = (offE + (size_t)NPIXC * 8 <= ws_size) ? 1 : 0;

  hipMemsetAsync(out, 0, sizeof(float), stream);   // k_match accumulates
  size_t zlen = (size_t)NIMG * CAP * 4 + 3ull * NIMG * NSLOT * 4;
  hipMemsetAsync(key, 0, zlen, stream);
  hipMemsetAsync(amin, 0xFF, (size_t)NIMG * NSLOT * 12, stream);
  hipMemsetAsync(nlab, 0, (size_t)NIMG * 4, stream);

  const int gC = NPIXC / 256;            // exact (k_angle/k_idx grids)
  const int gC4 = NPIXC / 4 / 256;       // float4 cimgcount grid
  const int gS = (NDN + 255) / 256;      // slot-compaction grid

  // first launch fuses init (labels from pred/tgt) with 16 prop iterations
  k_prop<<<PROPBLOCKS, 256, 0, stream>>>(A, A, pred, tgt, HALO, 1);
  float* src = A; float* dst = Bb;
  int done = HALO;
  while (done < PROP_ITERS) {
    int k = PROP_ITERS - done; if (k > HALO) k = HALO;
    k_prop<<<PROPBLOCKS, 256, 0, stream>>>(src, dst, pred, tgt, k, 0);
    float* t2 = src; src = dst; dst = t2;
    done += k;
  }
  float* Cm = dst;                       // spare buffer holds contour image
  k_cimgcount<<<gC4, 256, 0, stream>>>(src, Cm, key, cnt, sr, sc);
  k_compact<<<gS, 256, 0, stream>>>(key, cnt, sr, sc, nlab, labD, cntD, srD, scD, slotD);
  k_angle<<<gC, 256, 0, stream>>>(Cm, key, cnt, sr, sc, amin, encB, useEnc);
  k_idx<<<gC, 256, 0, stream>>>(Cm, key, cnt, sr, sc, amin, imin, encB, useEnc);
  k_match<<<BN, 256, 0, stream>>>(nlab, labD, cntD, srD, scD, slotD, imin, wp, out);
}